// Round 6
// baseline (162.287 us; speedup 1.0000x reference)
//
#include <hip/hip_runtime.h>

#define B_ROWS  16384
#define IN_DIM  1024
#define NEXP    8
#define HID     128
#define NCLS    1024
#define NPAIR   56
#define MAXW1   520   // max K1 work items: 32768/64 + 8
#define MAXW2   312   // max K2 work items: 16384/64 + 56

typedef __attribute__((ext_vector_type(8))) short bf16x8;
typedef __attribute__((ext_vector_type(4))) float f32x4;
typedef __attribute__((ext_vector_type(4))) unsigned int u32x4;
typedef __attribute__((ext_vector_type(8))) unsigned short u16x8;

__device__ __forceinline__ unsigned short f2bf(float f) {
  union { float f; unsigned u; } v; v.f = f;
  unsigned r = v.u + 0x7FFFu + ((v.u >> 16) & 1u);
  return (unsigned short)(r >> 16);
}

// XOR-swizzled LDS addressing (T2): linear rows, 8-short (16B) slots,
// slot ^= row&7. Row strides 128B/512B are 0 mod 32 banks, so banks depend
// only on the swizzled slot -> 2 lanes/bank on b128 ops (free).
__device__ __forceinline__ int sw64(int row, int sh) {   // 64-short rows
  return (row << 6) + ((((sh >> 3) ^ row) & 7) << 3) + (sh & 7);
}
__device__ __forceinline__ int sw256(int row, int sh) {  // 256-short rows
  return (row << 8) + ((((sh >> 3) ^ row) & 7) << 3) + (sh & 7) + ((sh >> 6) << 6);
}

// ---------------------------------------------------------------------------
// Transpose + fp32->bf16 convert: in [E][R][C] fp32 -> out [E][C][R] bf16.
// ---------------------------------------------------------------------------
__global__ __launch_bounds__(256) void transpose_cvt_kernel(
    const float* __restrict__ in, unsigned short* __restrict__ out,
    int R, int C) {
  __shared__ float tile[32][33];
  const int e = blockIdx.z;
  in  += (size_t)e * R * C;
  out += (size_t)e * R * C;
  const int c0 = blockIdx.x * 32, r0 = blockIdx.y * 32;
  const int tx = threadIdx.x, ty = threadIdx.y;
#pragma unroll
  for (int i = ty; i < 32; i += 8)
    tile[i][tx] = in[(size_t)(r0 + i) * C + c0 + tx];
  __syncthreads();
#pragma unroll
  for (int i = ty; i < 32; i += 8)
    out[(size_t)(c0 + i) * R + r0 + tx] = f2bf(tile[tx][i]);
}

// ---------------------------------------------------------------------------
// Gate compute v2: one wave per row, gw staged TRANSPOSED in LDS once per
// block (32 KB). Inner loop: scalar x load (coalesced) + 8 LDS reads at
// bank = lane&31 (2 lanes/bank = free). No atomics.
// ---------------------------------------------------------------------------
__global__ __launch_bounds__(256) void gate_compute(
    const float* __restrict__ x, const float* __restrict__ gw,
    const float* __restrict__ gb, float2* __restrict__ tval,
    unsigned char* __restrict__ pairid) {
  __shared__ float gws[NEXP * IN_DIM];   // [e][k], 32 KB
  const int t = threadIdx.x;
#pragma unroll
  for (int kk = 0; kk < 4; ++kk) {
    const int k = kk * 256 + t;
    const float4 g0 = *(const float4*)(gw + k * NEXP);
    const float4 g1 = *(const float4*)(gw + k * NEXP + 4);
    gws[0 * IN_DIM + k] = g0.x; gws[1 * IN_DIM + k] = g0.y;
    gws[2 * IN_DIM + k] = g0.z; gws[3 * IN_DIM + k] = g0.w;
    gws[4 * IN_DIM + k] = g1.x; gws[5 * IN_DIM + k] = g1.y;
    gws[6 * IN_DIM + k] = g1.z; gws[7 * IN_DIM + k] = g1.w;
  }
  __syncthreads();

  const int wave = t >> 6;
  const int lane = t & 63;
  const int row  = blockIdx.x * 4 + wave;

  const float* xr = x + (size_t)row * IN_DIM;
  float acc[NEXP];
#pragma unroll
  for (int e = 0; e < NEXP; ++e) acc[e] = 0.f;

  for (int j = lane; j < IN_DIM; j += 64) {
    const float xv = xr[j];
#pragma unroll
    for (int e = 0; e < NEXP; ++e)
      acc[e] = fmaf(xv, gws[e * IN_DIM + j], acc[e]);
  }
#pragma unroll
  for (int e = 0; e < NEXP; ++e) {
#pragma unroll
    for (int off = 32; off > 0; off >>= 1)
      acc[e] += __shfl_xor(acc[e], off);
  }

  if (lane == 0) {
    float l[NEXP];
#pragma unroll
    for (int e = 0; e < NEXP; ++e) l[e] = acc[e] + gb[e];
    float m = l[0];
#pragma unroll
    for (int e = 1; e < NEXP; ++e) m = fmaxf(m, l[e]);
    float p[NEXP], s = 0.f;
#pragma unroll
    for (int e = 0; e < NEXP; ++e) { p[e] = __expf(l[e] - m); s += p[e]; }
    const float inv = 1.f / s;
    int   i0 = 0;  float v0 = p[0];
#pragma unroll
    for (int e = 1; e < NEXP; ++e) if (p[e] > v0) { v0 = p[e]; i0 = e; }
    int   i1 = -1; float v1 = -1.f;
#pragma unroll
    for (int e = 0; e < NEXP; ++e)
      if (e != i0 && p[e] > v1) { v1 = p[e]; i1 = e; }
    tval[row] = make_float2(v0 * inv, v1 * inv);
    pairid[row] = (unsigned char)(i0 * 7 + i1 - (i1 > i0 ? 1 : 0));  // 0..55
  }
}

// ---------------------------------------------------------------------------
// Per-block partial histograms (init-free, no global atomics):
// partials[b][0..55] = pair counts, [56..63] = expert counts, for rows
// b*256..b*256+255.
// ---------------------------------------------------------------------------
__global__ __launch_bounds__(256) void hist_part_kernel(
    const unsigned char* __restrict__ pairid, int* __restrict__ partials) {
  __shared__ int h[64];
  const int t = threadIdx.x;
  if (t < 64) h[t] = 0;
  __syncthreads();
  const int p  = pairid[blockIdx.x * 256 + t];
  const int ea = p / 7, rem = p % 7;
  const int eb = rem + (rem >= ea ? 1 : 0);
  atomicAdd(&h[p], 1);
  atomicAdd(&h[56 + ea], 1);
  atomicAdd(&h[56 + eb], 1);
  __syncthreads();
  if (t < 64) partials[blockIdx.x * 64 + t] = h[t];
}

// ---------------------------------------------------------------------------
// Scan: 64 threads sum partials -> hist; thread 0 builds exclusive bases,
// scatter cursors, and exact work lists for K1/K2.
// ---------------------------------------------------------------------------
__global__ void scan_kernel(const int* __restrict__ partials,
                            int* __restrict__ hist, int* __restrict__ base,
                            int* __restrict__ csr, int* __restrict__ meta) {
  const int t = threadIdx.x;
  if (t < 64) {
    int s = 0;
    for (int b = 0; b < B_ROWS / 256; ++b) s += partials[b * 64 + t];
    hist[t] = s;
  }
  __syncthreads();
  if (t != 0) return;
  int accp = 0, acce = 0;
  for (int p = 0; p < NPAIR; ++p) { base[p] = accp; csr[p] = accp; accp += hist[p]; }
  for (int e = 0; e < NEXP; ++e) {
    base[56 + e] = acce; csr[56 + e] = acce; acce += hist[56 + e];
  }
  int n = 0;
  int* w1 = meta + 2;
  for (int e = 0; e < NEXP; ++e) {
    const int tiles = (hist[56 + e] + 63) >> 6;
    for (int i = 0; i < tiles; ++i) w1[n++] = (e << 16) | i;
  }
  meta[0] = n;
  n = 0;
  int* w2 = meta + 2 + MAXW1;
  for (int p = 0; p < NPAIR; ++p) {
    const int tiles = (hist[p] + 63) >> 6;
    for (int i = 0; i < tiles; ++i) w2[n++] = (p << 16) | i;
  }
  meta[1] = n;
}

// ---------------------------------------------------------------------------
// Scatter: per-block LDS histogram -> one aggregated global atomic per bin
// per block reserves a range; each row written exactly once per list.
// ---------------------------------------------------------------------------
__global__ __launch_bounds__(256) void scatter_kernel(
    const unsigned char* __restrict__ pairid, int* __restrict__ csr,
    int* __restrict__ elist, int* __restrict__ plist) {
  __shared__ int h[64], lbase[64];
  const int t = threadIdx.x;
  if (t < 64) h[t] = 0;
  __syncthreads();
  const int row = blockIdx.x * 256 + t;
  const int p  = pairid[row];
  const int ea = p / 7, rem = p % 7;
  const int eb = rem + (rem >= ea ? 1 : 0);
  const int op = atomicAdd(&h[p], 1);
  const int oa = atomicAdd(&h[56 + ea], 1);
  const int ob = atomicAdd(&h[56 + eb], 1);
  __syncthreads();
  if (t < 64) lbase[t] = h[t] ? atomicAdd(&csr[t], h[t]) : 0;
  __syncthreads();
  plist[lbase[p] + op]       = row;
  elist[lbase[56 + ea] + oa] = (row << 1);
  elist[lbase[56 + eb] + ob] = (row << 1) | 1;
}

// ---------------------------------------------------------------------------
// K1: hidden GEMM, expert-grouped. Block = 64 gathered rows of one expert.
// M=64, N=128(HID), K=1024, BK=64. Hg[row][slot][h] = relu(x@W1+b1)*gateval.
// ---------------------------------------------------------------------------
__global__ __launch_bounds__(256) void k1_hidden(
    const float* __restrict__ x, const unsigned short* __restrict__ w1bt,
    const float* __restrict__ b1, const float2* __restrict__ tval,
    const int* __restrict__ elist, const int* __restrict__ hist,
    const int* __restrict__ base, const int* __restrict__ meta,
    unsigned short* __restrict__ Hg) {
  const int b = blockIdx.x;
  if (b >= meta[0]) return;
  const int item = meta[2 + b];
  const int e = item >> 16, tile = item & 0xffff;
  const int start = tile * 64;
  const int nr = min(64, hist[56 + e] - start);

  __shared__ unsigned short As[64 * 64];    // swizzled
  __shared__ unsigned short Bs[128 * 64];   // swizzled
  __shared__ int rowl[64];

  const int t = threadIdx.x;
  if (t < 64) rowl[t] = elist[base[56 + e] + start + (t < nr ? t : 0)];
  __syncthreads();

  const int wid = t >> 6, l = t & 63;
  const int wr = wid >> 1, wc = wid & 1;
  const int lg = l >> 4,   ln = l & 15;

  f32x4 acc[2][4];
#pragma unroll
  for (int ms = 0; ms < 2; ++ms)
#pragma unroll
    for (int nf = 0; nf < 4; ++nf) acc[ms][nf] = (f32x4){0.f, 0.f, 0.f, 0.f};

  const int ai = t >> 2, aseg = t & 3;            // A: 4 thr/row, 16 floats each
  const float* asrc = x + (size_t)(rowl[ai] >> 1) * IN_DIM + aseg * 16;
  const int bn = t >> 1, bhf = t & 1;             // B: 2 thr/row, 32 shorts each
  const unsigned short* bsrc =
      w1bt + ((size_t)e * HID + bn) * IN_DIM + bhf * 32;

  for (int ks = 0; ks < 16; ++ks) {
    {
      const float4 f0 = *(const float4*)(asrc + ks * 64);
      const float4 f1 = *(const float4*)(asrc + ks * 64 + 4);
      const float4 f2 = *(const float4*)(asrc + ks * 64 + 8);
      const float4 f3 = *(const float4*)(asrc + ks * 64 + 12);
      u16x8 u0, u1;
      u0[0]=f2bf(f0.x); u0[1]=f2bf(f0.y); u0[2]=f2bf(f0.z); u0[3]=f2bf(f0.w);
      u0[4]=f2bf(f1.x); u0[5]=f2bf(f1.y); u0[6]=f2bf(f1.z); u0[7]=f2bf(f1.w);
      u1[0]=f2bf(f2.x); u1[1]=f2bf(f2.y); u1[2]=f2bf(f2.z); u1[3]=f2bf(f2.w);
      u1[4]=f2bf(f3.x); u1[5]=f2bf(f3.y); u1[6]=f2bf(f3.z); u1[7]=f2bf(f3.w);
      *(u16x8*)&As[sw64(ai, aseg * 16)]     = u0;
      *(u16x8*)&As[sw64(ai, aseg * 16 + 8)] = u1;
    }
    {
      const u32x4* bp = (const u32x4*)(bsrc + ks * 64);
#pragma unroll
      for (int j = 0; j < 4; ++j)
        *(u32x4*)&Bs[sw64(bn, bhf * 32 + j * 8)] = bp[j];
    }
    __syncthreads();
    bf16x8 af[2][2], bf[4][2];
#pragma unroll
    for (int ms = 0; ms < 2; ++ms)
#pragma unroll
      for (int kh = 0; kh < 2; ++kh)
        af[ms][kh] = *(const bf16x8*)&As[sw64(wr*32 + ms*16 + ln, kh*32 + lg*8)];
#pragma unroll
    for (int nf = 0; nf < 4; ++nf)
#pragma unroll
      for (int kh = 0; kh < 2; ++kh)
        bf[nf][kh] = *(const bf16x8*)&Bs[sw64(wc*64 + nf*16 + ln, kh*32 + lg*8)];
#pragma unroll
    for (int ms = 0; ms < 2; ++ms)
#pragma unroll
      for (int nf = 0; nf < 4; ++nf) {
        acc[ms][nf] = __builtin_amdgcn_mfma_f32_16x16x32_bf16(af[ms][0], bf[nf][0], acc[ms][nf], 0, 0, 0);
        acc[ms][nf] = __builtin_amdgcn_mfma_f32_16x16x32_bf16(af[ms][1], bf[nf][1], acc[ms][nf], 0, 0, 0);
      }
    __syncthreads();
  }

  float b1c[4];
#pragma unroll
  for (int nf = 0; nf < 4; ++nf) b1c[nf] = b1[e * HID + wc*64 + nf*16 + ln];

#pragma unroll
  for (int ms = 0; ms < 2; ++ms)
#pragma unroll
    for (int r = 0; r < 4; ++r) {
      const int li = wr*32 + ms*16 + lg*4 + r;
      if (li < nr) {
        const int packed = rowl[li];
        const int row = packed >> 1, slot = packed & 1;
        const float2 tv = tval[row];
        const float v = slot ? tv.y : tv.x;
#pragma unroll
        for (int nf = 0; nf < 4; ++nf) {
          const float h = fmaxf(acc[ms][nf][r] + b1c[nf], 0.f) * v;
          Hg[((size_t)row * 2 + slot) * HID + wc*64 + nf*16 + ln] = f2bf(h);
        }
      }
    }
}

// ---------------------------------------------------------------------------
// K2: output GEMM, pair-grouped. Block = 64 gathered rows x 128 out cols,
// K=256 (= [Hg slot0 | Hg slot1], matching [W2[ea]; W2[eb]]). One write/row.
// ---------------------------------------------------------------------------
__global__ __launch_bounds__(256) void k2_out(
    const unsigned short* __restrict__ Hg, const unsigned short* __restrict__ w2bt,
    const float* __restrict__ b2, const float2* __restrict__ tval,
    const int* __restrict__ plist, const int* __restrict__ hist,
    const int* __restrict__ base, const int* __restrict__ meta,
    float* __restrict__ out) {
  const int b = blockIdx.y;
  if (b >= meta[1]) return;
  const int item = meta[2 + MAXW1 + b];
  const int p = item >> 16, rt = item & 0xffff;
  const int ea = p / 7, rem = p % 7;
  const int eb = rem + (rem >= ea ? 1 : 0);
  const int start = rt * 64;
  const int nr = min(64, hist[p] - start);
  const int c0 = blockIdx.x * 128;

  __shared__ unsigned short Ah[64 * 256];   // swizzled, K=256 staged once
  __shared__ unsigned short Bs[128 * 64];   // swizzled, per-ks
  __shared__ int rowl[64];
  __shared__ float2 vals[64];

  const int t = threadIdx.x;
  if (t < 64) {
    const int r = plist[base[p] + start + (t < nr ? t : 0)];
    rowl[t] = r;
    vals[t] = tval[r];
  }
  __syncthreads();

  // stage A once: 64 rows x 256 shorts; 256 thr * 64 shorts (128B) each
  {
    const int i = t >> 2, q = t & 3;
    const u32x4* src = (const u32x4*)(Hg + (size_t)rowl[i] * 256 + q * 64);
#pragma unroll
    for (int j = 0; j < 8; ++j)
      *(u32x4*)&Ah[sw256(i, q * 64 + j * 8)] = src[j];
  }

  const int wid = t >> 6, l = t & 63;
  const int wr = wid >> 1, wc = wid & 1;
  const int lg = l >> 4,   ln = l & 15;

  f32x4 acc[2][4];
#pragma unroll
  for (int ms = 0; ms < 2; ++ms)
#pragma unroll
    for (int nf = 0; nf < 4; ++nf) acc[ms][nf] = (f32x4){0.f, 0.f, 0.f, 0.f};

  const int bn = t >> 1, bhf = t & 1;
  for (int ks = 0; ks < 4; ++ks) {
    const int ex = (ks < 2) ? ea : eb;
    const int hb = (ks & 1) * 64;
    {
      const u32x4* bp = (const u32x4*)(
          w2bt + ((size_t)ex * NCLS + c0 + bn) * HID + hb + bhf * 32);
#pragma unroll
      for (int j = 0; j < 4; ++j)
        *(u32x4*)&Bs[sw64(bn, bhf * 32 + j * 8)] = bp[j];
    }
    __syncthreads();
    bf16x8 af[2][2], bf[4][2];
#pragma unroll
    for (int ms = 0; ms < 2; ++ms)
#pragma unroll
      for (int kh = 0; kh < 2; ++kh)
        af[ms][kh] = *(const bf16x8*)&Ah[sw256(wr*32 + ms*16 + ln, ks*64 + kh*32 + lg*8)];
#pragma unroll
    for (int nf = 0; nf < 4; ++nf)
#pragma unroll
      for (int kh = 0; kh < 2; ++kh)
        bf[nf][kh] = *(const bf16x8*)&Bs[sw64(wc*64 + nf*16 + ln, kh*32 + lg*8)];
#pragma unroll
    for (int ms = 0; ms < 2; ++ms)
#pragma unroll
      for (int nf = 0; nf < 4; ++nf) {
        acc[ms][nf] = __builtin_amdgcn_mfma_f32_16x16x32_bf16(af[ms][0], bf[nf][0], acc[ms][nf], 0, 0, 0);
        acc[ms][nf] = __builtin_amdgcn_mfma_f32_16x16x32_bf16(af[ms][1], bf[nf][1], acc[ms][nf], 0, 0, 0);
      }
    __syncthreads();
  }

  float b2a[4], b2b[4];
#pragma unroll
  for (int nf = 0; nf < 4; ++nf) {
    const int c = c0 + wc*64 + nf*16 + ln;
    b2a[nf] = b2[ea * NCLS + c];
    b2b[nf] = b2[eb * NCLS + c];
  }
#pragma unroll
  for (int ms = 0; ms < 2; ++ms)
#pragma unroll
    for (int r = 0; r < 4; ++r) {
      const int li = wr*32 + ms*16 + lg*4 + r;
      if (li < nr) {
        const int row = rowl[li];
        const float2 v = vals[li];
#pragma unroll
        for (int nf = 0; nf < 4; ++nf) {
          const int c = c0 + wc*64 + nf*16 + ln;
          out[(size_t)row * NCLS + c] = acc[ms][nf][r] + v.x * b2a[nf] + v.y * b2b[nf];
        }
      }
    }
}

// ---------------------------------------------------------------------------
// gates_sum output
// ---------------------------------------------------------------------------
__global__ __launch_bounds__(256) void gates_out_kernel(
    const float2* __restrict__ tval, float* __restrict__ out) {
  __shared__ float r0[256], r1[256];
  float s0 = 0.f, s1 = 0.f;
  for (int i = threadIdx.x; i < B_ROWS; i += 256) {
    const float2 v = tval[i];
    s0 += v.x; s1 += v.y;
  }
  r0[threadIdx.x] = s0; r1[threadIdx.x] = s1;
  __syncthreads();
#pragma unroll
  for (int s = 128; s > 0; s >>= 1) {
    if (threadIdx.x < s) {
      r0[threadIdx.x] += r0[threadIdx.x + s];
      r1[threadIdx.x] += r1[threadIdx.x + s];
    }
    __syncthreads();
  }
  const float g0 = r0[0], g1 = r1[0];
  float* gout = out + (size_t)B_ROWS * NCLS;
  for (int c = threadIdx.x; c < NCLS; c += 256) {
    gout[c]        = g0;
    gout[NCLS + c] = g1;
  }
}

extern "C" void kernel_launch(void* const* d_in, const int* in_sizes, int n_in,
                              void* d_out, int out_size, void* d_ws, size_t ws_size,
                              hipStream_t stream) {
  const float* x   = (const float*)d_in[0];
  const float* gw  = (const float*)d_in[1];
  const float* gb  = (const float*)d_in[2];
  const float* w1  = (const float*)d_in[3];
  const float* b1  = (const float*)d_in[4];
  const float* w2  = (const float*)d_in[5];
  const float* b2  = (const float*)d_in[6];
  float* out = (float*)d_out;

  // ws layout (bytes), total ~12.95 MB. No buffer needs pre-zeroing:
  //   hist:     0..256        base: 256..512     csr: 512..768
  //   meta:     768..4104 (pad 4352)
  //   partials: 4352..20736     (64 blocks * 64 ints)
  //   pairid:   20736..37120    (16384 u8)
  //   tval:     37120..168192   (16384 float2)
  //   elist:    168192..299264  (32768 int, compact)
  //   plist:    299264..364800  (16384 int, compact)
  //   w1bt:     364800..2461952 ([8][128][1024] bf16)
  //   w2bt:     2461952..4559104([8][1024][128] bf16)
  //   Hg:       4559104..12947712 ([16384][2][128] bf16)
  char* ws = (char*)d_ws;
  int*            hist     = (int*)(ws);
  int*            base     = (int*)(ws + 256);
  int*            csr      = (int*)(ws + 512);
  int*            meta     = (int*)(ws + 768);
  int*            partials = (int*)(ws + 4352);
  unsigned char*  pairid   = (unsigned char*)(ws + 20736);
  float2*         tval     = (float2*)(ws + 37120);
  int*            elist    = (int*)(ws + 168192);
  int*            plist    = (int*)(ws + 299264);
  unsigned short* w1bt     = (unsigned short*)(ws + 364800);
  unsigned short* w2bt     = (unsigned short*)(ws + 2461952);
  unsigned short* Hg       = (unsigned short*)(ws + 4559104);

  dim3 tb(32, 8);
  transpose_cvt_kernel<<<dim3(HID / 32, IN_DIM / 32, NEXP), tb, 0, stream>>>(
      w1, w1bt, IN_DIM, HID);
  transpose_cvt_kernel<<<dim3(NCLS / 32, HID / 32, NEXP), tb, 0, stream>>>(
      w2, w2bt, HID, NCLS);

  gate_compute<<<B_ROWS / 4, 256, 0, stream>>>(x, gw, gb, tval, pairid);
  hist_part_kernel<<<B_ROWS / 256, 256, 0, stream>>>(pairid, partials);
  scan_kernel<<<1, 64, 0, stream>>>(partials, hist, base, csr, meta);
  scatter_kernel<<<B_ROWS / 256, 256, 0, stream>>>(pairid, csr, elist, plist);

  k1_hidden<<<MAXW1, 256, 0, stream>>>(x, w1bt, b1, tval, elist, hist, base,
                                       meta, Hg);
  k2_out<<<dim3(NCLS / 128, MAXW2), 256, 0, stream>>>(Hg, w2bt, b2, tval, plist,
                                                      hist, base, meta, out);

  gates_out_kernel<<<1, 256, 0, stream>>>(tval, out);
}

// Round 7
// 142.109 us; speedup vs baseline: 1.1420x; 1.1420x over previous
//
#include <hip/hip_runtime.h>

#define B_ROWS  16384
#define IN_DIM  1024
#define NEXP    8
#define HID     128
#define NCLS    1024
#define NPAIR   56
#define MAXW1   520   // max K1 work items: 32768/64 + 8
#define MAXW2   312   // max K2 work items: 16384/64 + 56

typedef __attribute__((ext_vector_type(8))) short bf16x8;
typedef __attribute__((ext_vector_type(4))) float f32x4;
typedef __attribute__((ext_vector_type(4))) unsigned int u32x4;
typedef __attribute__((ext_vector_type(8))) unsigned short u16x8;

__device__ __forceinline__ unsigned short f2bf(float f) {
  union { float f; unsigned u; } v; v.f = f;
  unsigned r = v.u + 0x7FFFu + ((v.u >> 16) & 1u);
  return (unsigned short)(r >> 16);
}

// XOR-swizzled LDS addressing (T2): linear rows, 8-short (16B) slots,
// slot ^= row&7. Row strides 128B/512B are 0 mod 32 banks, so banks depend
// only on the swizzled slot -> 2 lanes/bank on b128 ops (free).
__device__ __forceinline__ int sw64(int row, int sh) {   // 64-short rows
  return (row << 6) + ((((sh >> 3) ^ row) & 7) << 3) + (sh & 7);
}
__device__ __forceinline__ int sw256(int row, int sh) {  // 256-short rows
  return (row << 8) + ((((sh >> 3) ^ row) & 7) << 3) + (sh & 7) + ((sh >> 6) << 6);
}

// ---------------------------------------------------------------------------
// Transpose + fp32->bf16 convert: in [E][R][C] fp32 -> out [E][C][R] bf16.
// ---------------------------------------------------------------------------
__global__ __launch_bounds__(256) void transpose_cvt_kernel(
    const float* __restrict__ in, unsigned short* __restrict__ out,
    int R, int C) {
  __shared__ float tile[32][33];
  const int e = blockIdx.z;
  in  += (size_t)e * R * C;
  out += (size_t)e * R * C;
  const int c0 = blockIdx.x * 32, r0 = blockIdx.y * 32;
  const int tx = threadIdx.x, ty = threadIdx.y;
#pragma unroll
  for (int i = ty; i < 32; i += 8)
    tile[i][tx] = in[(size_t)(r0 + i) * C + c0 + tx];
  __syncthreads();
#pragma unroll
  for (int i = ty; i < 32; i += 8)
    out[(size_t)(c0 + i) * R + r0 + tx] = f2bf(tile[tx][i]);
}

// ---------------------------------------------------------------------------
// Gate + x->bf16 pass. 2 rows per wave, quarter-stride k split:
// lane l covers k in { j*256 + l*4 } for j=0..3. x loads = coalesced float4
// (1KB/instr); gws reads = stride-1 ds_read_b128, shared by both rows.
// Also writes xb (bf16 copy of x) if xb != nullptr.
// ---------------------------------------------------------------------------
__global__ __launch_bounds__(256) void gate_cvt(
    const float* __restrict__ x, const float* __restrict__ gw,
    const float* __restrict__ gb, unsigned short* __restrict__ xb,
    float2* __restrict__ tval, unsigned char* __restrict__ pairid) {
  __shared__ __attribute__((aligned(16))) float gws[NEXP][IN_DIM];  // 32 KB
  const int t = threadIdx.x;
#pragma unroll
  for (int kk = 0; kk < 4; ++kk) {
    const int k = kk * 256 + t;
    const float4 g0 = *(const float4*)(gw + k * NEXP);
    const float4 g1 = *(const float4*)(gw + k * NEXP + 4);
    gws[0][k] = g0.x; gws[1][k] = g0.y; gws[2][k] = g0.z; gws[3][k] = g0.w;
    gws[4][k] = g1.x; gws[5][k] = g1.y; gws[6][k] = g1.z; gws[7][k] = g1.w;
  }
  __syncthreads();

  const int wave = t >> 6, l = t & 63;
  const int r0 = blockIdx.x * 8 + wave * 2;   // rows r0, r0+1

  float4 xv0[4], xv1[4];
#pragma unroll
  for (int j = 0; j < 4; ++j) {
    xv0[j] = *(const float4*)(x + (size_t)r0 * IN_DIM + j * 256 + l * 4);
    xv1[j] = *(const float4*)(x + (size_t)(r0 + 1) * IN_DIM + j * 256 + l * 4);
  }

  if (xb) {   // bf16 copy, coalesced 8B/lane stores
#pragma unroll
    for (int j = 0; j < 4; ++j) {
      uint2 p0, p1;
      p0.x = (unsigned)f2bf(xv0[j].x) | ((unsigned)f2bf(xv0[j].y) << 16);
      p0.y = (unsigned)f2bf(xv0[j].z) | ((unsigned)f2bf(xv0[j].w) << 16);
      p1.x = (unsigned)f2bf(xv1[j].x) | ((unsigned)f2bf(xv1[j].y) << 16);
      p1.y = (unsigned)f2bf(xv1[j].z) | ((unsigned)f2bf(xv1[j].w) << 16);
      *(uint2*)(xb + (size_t)r0 * IN_DIM + j * 256 + l * 4)       = p0;
      *(uint2*)(xb + (size_t)(r0 + 1) * IN_DIM + j * 256 + l * 4) = p1;
    }
  }

  float a0[NEXP], a1[NEXP];
#pragma unroll
  for (int e = 0; e < NEXP; ++e) { a0[e] = 0.f; a1[e] = 0.f; }
#pragma unroll
  for (int e = 0; e < NEXP; ++e) {
#pragma unroll
    for (int j = 0; j < 4; ++j) {
      const float4 g = *(const float4*)&gws[e][j * 256 + l * 4];
      a0[e] = fmaf(xv0[j].x, g.x, a0[e]); a0[e] = fmaf(xv0[j].y, g.y, a0[e]);
      a0[e] = fmaf(xv0[j].z, g.z, a0[e]); a0[e] = fmaf(xv0[j].w, g.w, a0[e]);
      a1[e] = fmaf(xv1[j].x, g.x, a1[e]); a1[e] = fmaf(xv1[j].y, g.y, a1[e]);
      a1[e] = fmaf(xv1[j].z, g.z, a1[e]); a1[e] = fmaf(xv1[j].w, g.w, a1[e]);
    }
  }
#pragma unroll
  for (int e = 0; e < NEXP; ++e) {
#pragma unroll
    for (int off = 32; off > 0; off >>= 1) {
      a0[e] += __shfl_xor(a0[e], off);
      a1[e] += __shfl_xor(a1[e], off);
    }
  }

  if (l == 0) {
#pragma unroll
    for (int rr = 0; rr < 2; ++rr) {
      const float* a = rr ? a1 : a0;
      float lg[NEXP];
#pragma unroll
      for (int e = 0; e < NEXP; ++e) lg[e] = a[e] + gb[e];
      float m = lg[0];
#pragma unroll
      for (int e = 1; e < NEXP; ++e) m = fmaxf(m, lg[e]);
      float p[NEXP], s = 0.f;
#pragma unroll
      for (int e = 0; e < NEXP; ++e) { p[e] = __expf(lg[e] - m); s += p[e]; }
      const float inv = 1.f / s;
      int   i0 = 0;  float v0 = p[0];
#pragma unroll
      for (int e = 1; e < NEXP; ++e) if (p[e] > v0) { v0 = p[e]; i0 = e; }
      int   i1 = -1; float v1 = -1.f;
#pragma unroll
      for (int e = 0; e < NEXP; ++e)
        if (e != i0 && p[e] > v1) { v1 = p[e]; i1 = e; }
      tval[r0 + rr] = make_float2(v0 * inv, v1 * inv);
      pairid[r0 + rr] = (unsigned char)(i0 * 7 + i1 - (i1 > i0 ? 1 : 0));
    }
  }
}

// ---------------------------------------------------------------------------
// Per-block partial histograms (init-free, no global atomics).
// ---------------------------------------------------------------------------
__global__ __launch_bounds__(256) void hist_part_kernel(
    const unsigned char* __restrict__ pairid, int* __restrict__ partials) {
  __shared__ int h[64];
  const int t = threadIdx.x;
  if (t < 64) h[t] = 0;
  __syncthreads();
  const int p  = pairid[blockIdx.x * 256 + t];
  const int ea = p / 7, rem = p % 7;
  const int eb = rem + (rem >= ea ? 1 : 0);
  atomicAdd(&h[p], 1);
  atomicAdd(&h[56 + ea], 1);
  atomicAdd(&h[56 + eb], 1);
  __syncthreads();
  if (t < 64) partials[blockIdx.x * 64 + t] = h[t];
}

// ---------------------------------------------------------------------------
// Scan: sum partials -> hist; exclusive bases, cursors, exact work lists.
// ---------------------------------------------------------------------------
__global__ void scan_kernel(const int* __restrict__ partials,
                            int* __restrict__ hist, int* __restrict__ base,
                            int* __restrict__ csr, int* __restrict__ meta) {
  const int t = threadIdx.x;
  if (t < 64) {
    int s = 0;
    for (int b = 0; b < B_ROWS / 256; ++b) s += partials[b * 64 + t];
    hist[t] = s;
  }
  __syncthreads();
  if (t != 0) return;
  int accp = 0, acce = 0;
  for (int p = 0; p < NPAIR; ++p) { base[p] = accp; csr[p] = accp; accp += hist[p]; }
  for (int e = 0; e < NEXP; ++e) {
    base[56 + e] = acce; csr[56 + e] = acce; acce += hist[56 + e];
  }
  int n = 0;
  int* w1 = meta + 2;
  for (int e = 0; e < NEXP; ++e) {
    const int tiles = (hist[56 + e] + 63) >> 6;
    for (int i = 0; i < tiles; ++i) w1[n++] = (e << 16) | i;
  }
  meta[0] = n;
  n = 0;
  int* w2 = meta + 2 + MAXW1;
  for (int p = 0; p < NPAIR; ++p) {
    const int tiles = (hist[p] + 63) >> 6;
    for (int i = 0; i < tiles; ++i) w2[n++] = (p << 16) | i;
  }
  meta[1] = n;
}

// ---------------------------------------------------------------------------
// Scatter: per-block LDS histogram -> one aggregated atomic per bin per block.
// ---------------------------------------------------------------------------
__global__ __launch_bounds__(256) void scatter_kernel(
    const unsigned char* __restrict__ pairid, int* __restrict__ csr,
    int* __restrict__ elist, int* __restrict__ plist) {
  __shared__ int h[64], lbase[64];
  const int t = threadIdx.x;
  if (t < 64) h[t] = 0;
  __syncthreads();
  const int row = blockIdx.x * 256 + t;
  const int p  = pairid[row];
  const int ea = p / 7, rem = p % 7;
  const int eb = rem + (rem >= ea ? 1 : 0);
  const int op = atomicAdd(&h[p], 1);
  const int oa = atomicAdd(&h[56 + ea], 1);
  const int ob = atomicAdd(&h[56 + eb], 1);
  __syncthreads();
  if (t < 64) lbase[t] = h[t] ? atomicAdd(&csr[t], h[t]) : 0;
  __syncthreads();
  plist[lbase[p] + op]       = row;
  elist[lbase[56 + ea] + oa] = (row << 1);
  elist[lbase[56 + eb] + ob] = (row << 1) | 1;
}

// ---------------------------------------------------------------------------
// K1: hidden GEMM, expert-grouped. Block = 64 gathered rows of one expert.
// M=64, N=128(HID), K=1024, BK=64. A from xb (bf16) if XB, else from x (f32).
// ---------------------------------------------------------------------------
template <bool XB>
__global__ __launch_bounds__(256) void k1_hidden(
    const float* __restrict__ x, const unsigned short* __restrict__ xb,
    const unsigned short* __restrict__ w1bt, const float* __restrict__ b1,
    const float2* __restrict__ tval, const int* __restrict__ elist,
    const int* __restrict__ hist, const int* __restrict__ base,
    const int* __restrict__ meta, unsigned short* __restrict__ Hg) {
  const int b = blockIdx.x;
  if (b >= meta[0]) return;
  const int item = meta[2 + b];
  const int e = item >> 16, tile = item & 0xffff;
  const int start = tile * 64;
  const int nr = min(64, hist[56 + e] - start);

  __shared__ unsigned short As[64 * 64];    // swizzled
  __shared__ unsigned short Bs[128 * 64];   // swizzled
  __shared__ int rowl[64];

  const int t = threadIdx.x;
  if (t < 64) rowl[t] = elist[base[56 + e] + start + (t < nr ? t : 0)];
  __syncthreads();

  const int wid = t >> 6, l = t & 63;
  const int wr = wid >> 1, wc = wid & 1;
  const int lg = l >> 4,   ln = l & 15;

  f32x4 acc[2][4];
#pragma unroll
  for (int ms = 0; ms < 2; ++ms)
#pragma unroll
    for (int nf = 0; nf < 4; ++nf) acc[ms][nf] = (f32x4){0.f, 0.f, 0.f, 0.f};

  const int ai = t >> 2, aseg = t & 3;            // A: 4 thr/row, 16 elems each
  const float* asrcf = x + (size_t)(rowl[ai] >> 1) * IN_DIM + aseg * 16;
  const unsigned short* asrcb =
      xb + (size_t)(rowl[ai] >> 1) * IN_DIM + aseg * 16;
  const int bn = t >> 1, bhf = t & 1;             // B: 2 thr/row, 32 shorts each
  const unsigned short* bsrc =
      w1bt + ((size_t)e * HID + bn) * IN_DIM + bhf * 32;

  for (int ks = 0; ks < 16; ++ks) {
    if constexpr (XB) {
      const u32x4* ap = (const u32x4*)(asrcb + ks * 64);
      *(u32x4*)&As[sw64(ai, aseg * 16)]     = ap[0];
      *(u32x4*)&As[sw64(ai, aseg * 16 + 8)] = ap[1];
    } else {
      const float4 f0 = *(const float4*)(asrcf + ks * 64);
      const float4 f1 = *(const float4*)(asrcf + ks * 64 + 4);
      const float4 f2 = *(const float4*)(asrcf + ks * 64 + 8);
      const float4 f3 = *(const float4*)(asrcf + ks * 64 + 12);
      u16x8 u0, u1;
      u0[0]=f2bf(f0.x); u0[1]=f2bf(f0.y); u0[2]=f2bf(f0.z); u0[3]=f2bf(f0.w);
      u0[4]=f2bf(f1.x); u0[5]=f2bf(f1.y); u0[6]=f2bf(f1.z); u0[7]=f2bf(f1.w);
      u1[0]=f2bf(f2.x); u1[1]=f2bf(f2.y); u1[2]=f2bf(f2.z); u1[3]=f2bf(f2.w);
      u1[4]=f2bf(f3.x); u1[5]=f2bf(f3.y); u1[6]=f2bf(f3.z); u1[7]=f2bf(f3.w);
      *(u16x8*)&As[sw64(ai, aseg * 16)]     = u0;
      *(u16x8*)&As[sw64(ai, aseg * 16 + 8)] = u1;
    }
    {
      const u32x4* bp = (const u32x4*)(bsrc + ks * 64);
#pragma unroll
      for (int j = 0; j < 4; ++j)
        *(u32x4*)&Bs[sw64(bn, bhf * 32 + j * 8)] = bp[j];
    }
    __syncthreads();
    bf16x8 af[2][2], bf[4][2];
#pragma unroll
    for (int ms = 0; ms < 2; ++ms)
#pragma unroll
      for (int kh = 0; kh < 2; ++kh)
        af[ms][kh] = *(const bf16x8*)&As[sw64(wr*32 + ms*16 + ln, kh*32 + lg*8)];
#pragma unroll
    for (int nf = 0; nf < 4; ++nf)
#pragma unroll
      for (int kh = 0; kh < 2; ++kh)
        bf[nf][kh] = *(const bf16x8*)&Bs[sw64(wc*64 + nf*16 + ln, kh*32 + lg*8)];
#pragma unroll
    for (int ms = 0; ms < 2; ++ms)
#pragma unroll
      for (int nf = 0; nf < 4; ++nf) {
        acc[ms][nf] = __builtin_amdgcn_mfma_f32_16x16x32_bf16(af[ms][0], bf[nf][0], acc[ms][nf], 0, 0, 0);
        acc[ms][nf] = __builtin_amdgcn_mfma_f32_16x16x32_bf16(af[ms][1], bf[nf][1], acc[ms][nf], 0, 0, 0);
      }
    __syncthreads();
  }

  float b1c[4];
#pragma unroll
  for (int nf = 0; nf < 4; ++nf) b1c[nf] = b1[e * HID + wc*64 + nf*16 + ln];

#pragma unroll
  for (int ms = 0; ms < 2; ++ms)
#pragma unroll
    for (int r = 0; r < 4; ++r) {
      const int li = wr*32 + ms*16 + lg*4 + r;
      if (li < nr) {
        const int packed = rowl[li];
        const int row = packed >> 1, slot = packed & 1;
        const float2 tv = tval[row];
        const float v = slot ? tv.y : tv.x;
#pragma unroll
        for (int nf = 0; nf < 4; ++nf) {
          const float h = fmaxf(acc[ms][nf][r] + b1c[nf], 0.f) * v;
          Hg[((size_t)row * 2 + slot) * HID + wc*64 + nf*16 + ln] = f2bf(h);
        }
      }
    }
}

// ---------------------------------------------------------------------------
// K2: output GEMM, pair-grouped. Block = 64 gathered rows x 128 out cols,
// K=256 (= [Hg slot0 | Hg slot1], matching [W2[ea]; W2[eb]]). One write/row.
// ---------------------------------------------------------------------------
__global__ __launch_bounds__(256) void k2_out(
    const unsigned short* __restrict__ Hg, const unsigned short* __restrict__ w2bt,
    const float* __restrict__ b2, const float2* __restrict__ tval,
    const int* __restrict__ plist, const int* __restrict__ hist,
    const int* __restrict__ base, const int* __restrict__ meta,
    float* __restrict__ out) {
  const int b = blockIdx.y;
  if (b >= meta[1]) return;
  const int item = meta[2 + MAXW1 + b];
  const int p = item >> 16, rt = item & 0xffff;
  const int ea = p / 7, rem = p % 7;
  const int eb = rem + (rem >= ea ? 1 : 0);
  const int start = rt * 64;
  const int nr = min(64, hist[p] - start);
  const int c0 = blockIdx.x * 128;

  __shared__ unsigned short Ah[64 * 256];   // swizzled, K=256 staged once
  __shared__ unsigned short Bs[128 * 64];   // swizzled, per-ks
  __shared__ int rowl[64];
  __shared__ float2 vals[64];

  const int t = threadIdx.x;
  if (t < 64) {
    const int r = plist[base[p] + start + (t < nr ? t : 0)];
    rowl[t] = r;
    vals[t] = tval[r];
  }
  __syncthreads();

  {
    const int i = t >> 2, q = t & 3;
    const u32x4* src = (const u32x4*)(Hg + (size_t)rowl[i] * 256 + q * 64);
#pragma unroll
    for (int j = 0; j < 8; ++j)
      *(u32x4*)&Ah[sw256(i, q * 64 + j * 8)] = src[j];
  }

  const int wid = t >> 6, l = t & 63;
  const int wr = wid >> 1, wc = wid & 1;
  const int lg = l >> 4,   ln = l & 15;

  f32x4 acc[2][4];
#pragma unroll
  for (int ms = 0; ms < 2; ++ms)
#pragma unroll
    for (int nf = 0; nf < 4; ++nf) acc[ms][nf] = (f32x4){0.f, 0.f, 0.f, 0.f};

  const int bn = t >> 1, bhf = t & 1;
  for (int ks = 0; ks < 4; ++ks) {
    const int ex = (ks < 2) ? ea : eb;
    const int hb = (ks & 1) * 64;
    {
      const u32x4* bp = (const u32x4*)(
          w2bt + ((size_t)ex * NCLS + c0 + bn) * HID + hb + bhf * 32);
#pragma unroll
      for (int j = 0; j < 4; ++j)
        *(u32x4*)&Bs[sw64(bn, bhf * 32 + j * 8)] = bp[j];
    }
    __syncthreads();
    bf16x8 af[2][2], bf[4][2];
#pragma unroll
    for (int ms = 0; ms < 2; ++ms)
#pragma unroll
      for (int kh = 0; kh < 2; ++kh)
        af[ms][kh] = *(const bf16x8*)&Ah[sw256(wr*32 + ms*16 + ln, ks*64 + kh*32 + lg*8)];
#pragma unroll
    for (int nf = 0; nf < 4; ++nf)
#pragma unroll
      for (int kh = 0; kh < 2; ++kh)
        bf[nf][kh] = *(const bf16x8*)&Bs[sw64(wc*64 + nf*16 + ln, kh*32 + lg*8)];
#pragma unroll
    for (int ms = 0; ms < 2; ++ms)
#pragma unroll
      for (int nf = 0; nf < 4; ++nf) {
        acc[ms][nf] = __builtin_amdgcn_mfma_f32_16x16x32_bf16(af[ms][0], bf[nf][0], acc[ms][nf], 0, 0, 0);
        acc[ms][nf] = __builtin_amdgcn_mfma_f32_16x16x32_bf16(af[ms][1], bf[nf][1], acc[ms][nf], 0, 0, 0);
      }
    __syncthreads();
  }

  float b2a[4], b2b[4];
#pragma unroll
  for (int nf = 0; nf < 4; ++nf) {
    const int c = c0 + wc*64 + nf*16 + ln;
    b2a[nf] = b2[ea * NCLS + c];
    b2b[nf] = b2[eb * NCLS + c];
  }
#pragma unroll
  for (int ms = 0; ms < 2; ++ms)
#pragma unroll
    for (int r = 0; r < 4; ++r) {
      const int li = wr*32 + ms*16 + lg*4 + r;
      if (li < nr) {
        const int row = rowl[li];
        const float2 v = vals[li];
#pragma unroll
        for (int nf = 0; nf < 4; ++nf) {
          const int c = c0 + wc*64 + nf*16 + ln;
          out[(size_t)row * NCLS + c] = acc[ms][nf][r] + v.x * b2a[nf] + v.y * b2b[nf];
        }
      }
    }
}

// ---------------------------------------------------------------------------
// gates_sum output
// ---------------------------------------------------------------------------
__global__ __launch_bounds__(256) void gates_out_kernel(
    const float2* __restrict__ tval, float* __restrict__ out) {
  __shared__ float r0[256], r1[256];
  float s0 = 0.f, s1 = 0.f;
  for (int i = threadIdx.x; i < B_ROWS; i += 256) {
    const float2 v = tval[i];
    s0 += v.x; s1 += v.y;
  }
  r0[threadIdx.x] = s0; r1[threadIdx.x] = s1;
  __syncthreads();
#pragma unroll
  for (int s = 128; s > 0; s >>= 1) {
    if (threadIdx.x < s) {
      r0[threadIdx.x] += r0[threadIdx.x + s];
      r1[threadIdx.x] += r1[threadIdx.x + s];
    }
    __syncthreads();
  }
  const float g0 = r0[0], g1 = r1[0];
  float* gout = out + (size_t)B_ROWS * NCLS;
  for (int c = threadIdx.x; c < NCLS; c += 256) {
    gout[c]        = g0;
    gout[NCLS + c] = g1;
  }
}

extern "C" void kernel_launch(void* const* d_in, const int* in_sizes, int n_in,
                              void* d_out, int out_size, void* d_ws, size_t ws_size,
                              hipStream_t stream) {
  const float* x   = (const float*)d_in[0];
  const float* gw  = (const float*)d_in[1];
  const float* gb  = (const float*)d_in[2];
  const float* w1  = (const float*)d_in[3];
  const float* b1  = (const float*)d_in[4];
  const float* w2  = (const float*)d_in[5];
  const float* b2  = (const float*)d_in[6];
  float* out = (float*)d_out;

  // ws layout (bytes). Nothing needs pre-zeroing:
  //   hist:     0..256        base: 256..512     csr: 512..768
  //   meta:     768..4104 (pad 4352)
  //   partials: 4352..20736     (64 blocks * 64 ints)
  //   pairid:   20736..37120    (16384 u8)
  //   tval:     37120..168192   (16384 float2)
  //   elist:    168192..299264  (32768 int)
  //   plist:    299264..364800  (16384 int)
  //   w1bt:     364800..2461952 ([8][128][1024] bf16)
  //   w2bt:     2461952..4559104([8][1024][128] bf16)
  //   Hg:       4559104..12947712 ([16384][2][128] bf16)
  //   xb:       12947712..46502144 ([16384][1024] bf16, optional)
  char* ws = (char*)d_ws;
  int*            hist     = (int*)(ws);
  int*            base     = (int*)(ws + 256);
  int*            csr      = (int*)(ws + 512);
  int*            meta     = (int*)(ws + 768);
  int*            partials = (int*)(ws + 4352);
  unsigned char*  pairid   = (unsigned char*)(ws + 20736);
  float2*         tval     = (float2*)(ws + 37120);
  int*            elist    = (int*)(ws + 168192);
  int*            plist    = (int*)(ws + 299264);
  unsigned short* w1bt     = (unsigned short*)(ws + 364800);
  unsigned short* w2bt     = (unsigned short*)(ws + 2461952);
  unsigned short* Hg       = (unsigned short*)(ws + 4559104);
  const bool use_xb = (ws_size >= (size_t)46502144);
  unsigned short* xb = use_xb ? (unsigned short*)(ws + 12947712) : nullptr;

  dim3 tb(32, 8);
  transpose_cvt_kernel<<<dim3(HID / 32, IN_DIM / 32, NEXP), tb, 0, stream>>>(
      w1, w1bt, IN_DIM, HID);
  transpose_cvt_kernel<<<dim3(NCLS / 32, HID / 32, NEXP), tb, 0, stream>>>(
      w2, w2bt, HID, NCLS);

  gate_cvt<<<B_ROWS / 8, 256, 0, stream>>>(x, gw, gb, xb, tval, pairid);
  hist_part_kernel<<<B_ROWS / 256, 256, 0, stream>>>(pairid, partials);
  scan_kernel<<<1, 64, 0, stream>>>(partials, hist, base, csr, meta);
  scatter_kernel<<<B_ROWS / 256, 256, 0, stream>>>(pairid, csr, elist, plist);

  if (use_xb)
    k1_hidden<true><<<MAXW1, 256, 0, stream>>>(x, xb, w1bt, b1, tval, elist,
                                               hist, base, meta, Hg);
  else
    k1_hidden<false><<<MAXW1, 256, 0, stream>>>(x, xb, w1bt, b1, tval, elist,
                                                hist, base, meta, Hg);
  k2_out<<<dim3(NCLS / 128, MAXW2), 256, 0, stream>>>(Hg, w2bt, b2, tval, plist,
                                                      hist, base, meta, out);

  gates_out_kernel<<<1, 256, 0, stream>>>(tval, out);
}

// Round 8
// 117.984 us; speedup vs baseline: 1.3755x; 1.2045x over previous
//
#include <hip/hip_runtime.h>

#define B_ROWS  16384
#define IN_DIM  1024
#define NEXP    8
#define HID     128
#define NCLS    1024
#define NPAIR   56
#define MAXW1   520   // max K1 work items: 32768/64 + 8
#define MAXW2   312   // max K2 work items: 16384/64 + 56

#define GATE_BLOCKS (B_ROWS / 8)                       // 2048
#define W1T_BLOCKS  (NEXP * (IN_DIM / 32) * (HID / 32)) // 1024
#define W2T_BLOCKS  (NEXP * (HID / 32) * (NCLS / 32))   // 1024

typedef __attribute__((ext_vector_type(8))) short bf16x8;
typedef __attribute__((ext_vector_type(4))) float f32x4;
typedef __attribute__((ext_vector_type(4))) unsigned int u32x4;
typedef __attribute__((ext_vector_type(8))) unsigned short u16x8;

__device__ __forceinline__ unsigned short f2bf(float f) {
  union { float f; unsigned u; } v; v.f = f;
  unsigned r = v.u + 0x7FFFu + ((v.u >> 16) & 1u);
  return (unsigned short)(r >> 16);
}

// XOR-swizzled LDS addressing (T2): linear rows, 8-short (16B) slots,
// slot ^= row&7.
__device__ __forceinline__ int sw64(int row, int sh) {   // 64-short rows
  return (row << 6) + ((((sh >> 3) ^ row) & 7) << 3) + (sh & 7);
}
__device__ __forceinline__ int sw256(int row, int sh) {  // 256-short rows
  return (row << 8) + ((((sh >> 3) ^ row) & 7) << 3) + (sh & 7) + ((sh >> 6) << 6);
}

// ---------------------------------------------------------------------------
// Fused prep: blocks [0,2048) gate+x->bf16; [2048,3072) w1 transpose;
// [3072,4096) w2 transpose. All independent work, one launch.
// ---------------------------------------------------------------------------
__global__ __launch_bounds__(256) void prep_kernel(
    const float* __restrict__ x, const float* __restrict__ gw,
    const float* __restrict__ gb, const float* __restrict__ w1,
    const float* __restrict__ w2, unsigned short* __restrict__ xb,
    unsigned short* __restrict__ w1bt, unsigned short* __restrict__ w2bt,
    float2* __restrict__ tval, unsigned char* __restrict__ pairid) {
  __shared__ __attribute__((aligned(16))) unsigned char pmem[NEXP * IN_DIM * 4];
  const int bid = blockIdx.x;
  const int t = threadIdx.x;

  if (bid < GATE_BLOCKS) {
    // ---------------- gate + convert ----------------
    float (*gws)[IN_DIM] = (float(*)[IN_DIM])pmem;   // 32 KB
#pragma unroll
    for (int kk = 0; kk < 4; ++kk) {
      const int k = kk * 256 + t;
      const float4 g0 = *(const float4*)(gw + k * NEXP);
      const float4 g1 = *(const float4*)(gw + k * NEXP + 4);
      gws[0][k] = g0.x; gws[1][k] = g0.y; gws[2][k] = g0.z; gws[3][k] = g0.w;
      gws[4][k] = g1.x; gws[5][k] = g1.y; gws[6][k] = g1.z; gws[7][k] = g1.w;
    }
    __syncthreads();

    const int wave = t >> 6, l = t & 63;
    const int r0 = bid * 8 + wave * 2;

    float4 xv0[4], xv1[4];
#pragma unroll
    for (int j = 0; j < 4; ++j) {
      xv0[j] = *(const float4*)(x + (size_t)r0 * IN_DIM + j * 256 + l * 4);
      xv1[j] = *(const float4*)(x + (size_t)(r0 + 1) * IN_DIM + j * 256 + l * 4);
    }

    if (xb) {
#pragma unroll
      for (int j = 0; j < 4; ++j) {
        uint2 p0, p1;
        p0.x = (unsigned)f2bf(xv0[j].x) | ((unsigned)f2bf(xv0[j].y) << 16);
        p0.y = (unsigned)f2bf(xv0[j].z) | ((unsigned)f2bf(xv0[j].w) << 16);
        p1.x = (unsigned)f2bf(xv1[j].x) | ((unsigned)f2bf(xv1[j].y) << 16);
        p1.y = (unsigned)f2bf(xv1[j].z) | ((unsigned)f2bf(xv1[j].w) << 16);
        *(uint2*)(xb + (size_t)r0 * IN_DIM + j * 256 + l * 4)       = p0;
        *(uint2*)(xb + (size_t)(r0 + 1) * IN_DIM + j * 256 + l * 4) = p1;
      }
    }

    float a0[NEXP], a1[NEXP];
#pragma unroll
    for (int e = 0; e < NEXP; ++e) { a0[e] = 0.f; a1[e] = 0.f; }
#pragma unroll
    for (int e = 0; e < NEXP; ++e) {
#pragma unroll
      for (int j = 0; j < 4; ++j) {
        const float4 g = *(const float4*)&gws[e][j * 256 + l * 4];
        a0[e] = fmaf(xv0[j].x, g.x, a0[e]); a0[e] = fmaf(xv0[j].y, g.y, a0[e]);
        a0[e] = fmaf(xv0[j].z, g.z, a0[e]); a0[e] = fmaf(xv0[j].w, g.w, a0[e]);
        a1[e] = fmaf(xv1[j].x, g.x, a1[e]); a1[e] = fmaf(xv1[j].y, g.y, a1[e]);
        a1[e] = fmaf(xv1[j].z, g.z, a1[e]); a1[e] = fmaf(xv1[j].w, g.w, a1[e]);
      }
    }
#pragma unroll
    for (int e = 0; e < NEXP; ++e) {
#pragma unroll
      for (int off = 32; off > 0; off >>= 1) {
        a0[e] += __shfl_xor(a0[e], off);
        a1[e] += __shfl_xor(a1[e], off);
      }
    }

    if (l == 0) {
#pragma unroll
      for (int rr = 0; rr < 2; ++rr) {
        const float* a = rr ? a1 : a0;
        float lg[NEXP];
#pragma unroll
        for (int e = 0; e < NEXP; ++e) lg[e] = a[e] + gb[e];
        float m = lg[0];
#pragma unroll
        for (int e = 1; e < NEXP; ++e) m = fmaxf(m, lg[e]);
        float p[NEXP], s = 0.f;
#pragma unroll
        for (int e = 0; e < NEXP; ++e) { p[e] = __expf(lg[e] - m); s += p[e]; }
        const float inv = 1.f / s;
        int   i0 = 0;  float v0 = p[0];
#pragma unroll
        for (int e = 1; e < NEXP; ++e) if (p[e] > v0) { v0 = p[e]; i0 = e; }
        int   i1 = -1; float v1 = -1.f;
#pragma unroll
        for (int e = 0; e < NEXP; ++e)
          if (e != i0 && p[e] > v1) { v1 = p[e]; i1 = e; }
        tval[r0 + rr] = make_float2(v0 * inv, v1 * inv);
        pairid[r0 + rr] = (unsigned char)(i0 * 7 + i1 - (i1 > i0 ? 1 : 0));
      }
    }
  } else {
    // ---------------- weight transpose + cvt ----------------
    float (*tile)[33] = (float(*)[33])pmem;   // 4.2 KB of the union
    const float* src; unsigned short* dst;
    int R, C, r0, c0, e;
    if (bid < GATE_BLOCKS + W1T_BLOCKS) {
      const int b1 = bid - GATE_BLOCKS;
      e = b1 >> 7; const int rem = b1 & 127;
      R = IN_DIM; C = HID;
      c0 = (rem & 3) * 32; r0 = (rem >> 2) * 32;
      src = w1; dst = w1bt;
    } else {
      const int b2 = bid - GATE_BLOCKS - W1T_BLOCKS;
      e = b2 >> 7; const int rem = b2 & 127;
      R = HID; C = NCLS;
      c0 = (rem & 31) * 32; r0 = (rem >> 5) * 32;
      src = w2; dst = w2bt;
    }
    src += (size_t)e * R * C;
    dst += (size_t)e * R * C;
    const int tx = t & 31, ty = t >> 5;
#pragma unroll
    for (int i = ty; i < 32; i += 8)
      tile[i][tx] = src[(size_t)(r0 + i) * C + c0 + tx];
    __syncthreads();
#pragma unroll
    for (int i = ty; i < 32; i += 8)
      dst[(size_t)(c0 + i) * R + r0 + tx] = f2bf(tile[tx][i]);
  }
}

// ---------------------------------------------------------------------------
// Per-block partial histograms + partial tval sums (init-free).
// ---------------------------------------------------------------------------
__global__ __launch_bounds__(256) void hist_part_kernel(
    const unsigned char* __restrict__ pairid, const float2* __restrict__ tval,
    int* __restrict__ partials, float2* __restrict__ psum) {
  __shared__ int h[64];
  __shared__ float s0a[256], s1a[256];
  const int t = threadIdx.x;
  if (t < 64) h[t] = 0;
  __syncthreads();
  const int row = blockIdx.x * 256 + t;
  const int p  = pairid[row];
  const int ea = p / 7, rem = p % 7;
  const int eb = rem + (rem >= ea ? 1 : 0);
  atomicAdd(&h[p], 1);
  atomicAdd(&h[56 + ea], 1);
  atomicAdd(&h[56 + eb], 1);
  const float2 v = tval[row];
  s0a[t] = v.x; s1a[t] = v.y;
  __syncthreads();
#pragma unroll
  for (int s = 128; s > 0; s >>= 1) {
    if (t < s) { s0a[t] += s0a[t + s]; s1a[t] += s1a[t + s]; }
    __syncthreads();
  }
  if (t < 64) partials[blockIdx.x * 64 + t] = h[t];
  if (t == 0) psum[blockIdx.x] = make_float2(s0a[0], s1a[0]);
}

// ---------------------------------------------------------------------------
// Scan: sum partials -> hist; exclusive bases, cursors, exact work lists;
// also reduces psum and writes the gates_sum output rows.
// ---------------------------------------------------------------------------
__global__ void scan_kernel(const int* __restrict__ partials,
                            const float2* __restrict__ psum,
                            int* __restrict__ hist, int* __restrict__ base,
                            int* __restrict__ csr, int* __restrict__ meta,
                            float* __restrict__ out) {
  const int t = threadIdx.x;
  __shared__ float gg[2];
  if (t < 64) {
    int s = 0;
    for (int b = 0; b < B_ROWS / 256; ++b) s += partials[b * 64 + t];
    hist[t] = s;
  }
  if (t == 0) {
    float g0 = 0.f, g1 = 0.f;
    for (int b = 0; b < B_ROWS / 256; ++b) { g0 += psum[b].x; g1 += psum[b].y; }
    gg[0] = g0; gg[1] = g1;
  }
  __syncthreads();
  float* gout = out + (size_t)B_ROWS * NCLS;
  for (int c = t; c < NCLS; c += 64) {
    gout[c]        = gg[0];
    gout[NCLS + c] = gg[1];
  }
  if (t != 0) return;
  int accp = 0, acce = 0;
  for (int p = 0; p < NPAIR; ++p) { base[p] = accp; csr[p] = accp; accp += hist[p]; }
  for (int e = 0; e < NEXP; ++e) {
    base[56 + e] = acce; csr[56 + e] = acce; acce += hist[56 + e];
  }
  int n = 0;
  int* w1 = meta + 2;
  for (int e = 0; e < NEXP; ++e) {
    const int tiles = (hist[56 + e] + 63) >> 6;
    for (int i = 0; i < tiles; ++i) w1[n++] = (e << 16) | i;
  }
  meta[0] = n;
  n = 0;
  int* w2 = meta + 2 + MAXW1;
  for (int p = 0; p < NPAIR; ++p) {
    const int tiles = (hist[p] + 63) >> 6;
    for (int i = 0; i < tiles; ++i) w2[n++] = (p << 16) | i;
  }
  meta[1] = n;
}

// ---------------------------------------------------------------------------
// Scatter: per-block LDS histogram -> one aggregated atomic per bin per block.
// ---------------------------------------------------------------------------
__global__ __launch_bounds__(256) void scatter_kernel(
    const unsigned char* __restrict__ pairid, int* __restrict__ csr,
    int* __restrict__ elist, int* __restrict__ plist) {
  __shared__ int h[64], lbase[64];
  const int t = threadIdx.x;
  if (t < 64) h[t] = 0;
  __syncthreads();
  const int row = blockIdx.x * 256 + t;
  const int p  = pairid[row];
  const int ea = p / 7, rem = p % 7;
  const int eb = rem + (rem >= ea ? 1 : 0);
  const int op = atomicAdd(&h[p], 1);
  const int oa = atomicAdd(&h[56 + ea], 1);
  const int ob = atomicAdd(&h[56 + eb], 1);
  __syncthreads();
  if (t < 64) lbase[t] = h[t] ? atomicAdd(&csr[t], h[t]) : 0;
  __syncthreads();
  plist[lbase[p] + op]       = row;
  elist[lbase[56 + ea] + oa] = (row << 1);
  elist[lbase[56 + eb] + ob] = (row << 1) | 1;
}

// ---------------------------------------------------------------------------
// K1: hidden GEMM, expert-grouped. XB path: 2-phase reg prefetch (T14) —
// next tile's global loads issued before current tile's ds_read+MFMA.
// ---------------------------------------------------------------------------
template <bool XB>
__global__ __launch_bounds__(256) void k1_hidden(
    const float* __restrict__ x, const unsigned short* __restrict__ xb,
    const unsigned short* __restrict__ w1bt, const float* __restrict__ b1,
    const float2* __restrict__ tval, const int* __restrict__ elist,
    const int* __restrict__ hist, const int* __restrict__ base,
    const int* __restrict__ meta, unsigned short* __restrict__ Hg) {
  const int b = blockIdx.x;
  if (b >= meta[0]) return;
  const int item = meta[2 + b];
  const int e = item >> 16, tile = item & 0xffff;
  const int start = tile * 64;
  const int nr = min(64, hist[56 + e] - start);

  __shared__ unsigned short As[64 * 64];    // swizzled
  __shared__ unsigned short Bs[128 * 64];   // swizzled
  __shared__ int rowl[64];

  const int t = threadIdx.x;
  if (t < 64) rowl[t] = elist[base[56 + e] + start + (t < nr ? t : 0)];
  __syncthreads();

  const int wid = t >> 6, l = t & 63;
  const int wr = wid >> 1, wc = wid & 1;
  const int lg = l >> 4,   ln = l & 15;

  f32x4 acc[2][4];
#pragma unroll
  for (int ms = 0; ms < 2; ++ms)
#pragma unroll
    for (int nf = 0; nf < 4; ++nf) acc[ms][nf] = (f32x4){0.f, 0.f, 0.f, 0.f};

  const int ai = t >> 2, aseg = t & 3;
  const float* asrcf = x + (size_t)(rowl[ai] >> 1) * IN_DIM + aseg * 16;
  const unsigned short* asrcb =
      xb + (size_t)(rowl[ai] >> 1) * IN_DIM + aseg * 16;
  const int bn = t >> 1, bhf = t & 1;
  const unsigned short* bsrc =
      w1bt + ((size_t)e * HID + bn) * IN_DIM + bhf * 32;

  if constexpr (XB) {
    u32x4 areg[2], breg[4];
    {
      const u32x4* ap = (const u32x4*)(asrcb);
      areg[0] = ap[0]; areg[1] = ap[1];
      const u32x4* bp = (const u32x4*)(bsrc);
#pragma unroll
      for (int j = 0; j < 4; ++j) breg[j] = bp[j];
    }
    for (int ks = 0; ks < 16; ++ks) {
      *(u32x4*)&As[sw64(ai, aseg * 16)]     = areg[0];
      *(u32x4*)&As[sw64(ai, aseg * 16 + 8)] = areg[1];
#pragma unroll
      for (int j = 0; j < 4; ++j)
        *(u32x4*)&Bs[sw64(bn, bhf * 32 + j * 8)] = breg[j];
      __syncthreads();
      if (ks < 15) {   // issue next tile; latency hides under MFMA below
        const u32x4* ap = (const u32x4*)(asrcb + (ks + 1) * 64);
        areg[0] = ap[0]; areg[1] = ap[1];
        const u32x4* bp = (const u32x4*)(bsrc + (ks + 1) * 64);
#pragma unroll
        for (int j = 0; j < 4; ++j) breg[j] = bp[j];
      }
      bf16x8 af[2][2], bf[4][2];
#pragma unroll
      for (int ms = 0; ms < 2; ++ms)
#pragma unroll
        for (int kh = 0; kh < 2; ++kh)
          af[ms][kh] = *(const bf16x8*)&As[sw64(wr*32 + ms*16 + ln, kh*32 + lg*8)];
#pragma unroll
      for (int nf = 0; nf < 4; ++nf)
#pragma unroll
        for (int kh = 0; kh < 2; ++kh)
          bf[nf][kh] = *(const bf16x8*)&Bs[sw64(wc*64 + nf*16 + ln, kh*32 + lg*8)];
#pragma unroll
      for (int ms = 0; ms < 2; ++ms)
#pragma unroll
        for (int nf = 0; nf < 4; ++nf) {
          acc[ms][nf] = __builtin_amdgcn_mfma_f32_16x16x32_bf16(af[ms][0], bf[nf][0], acc[ms][nf], 0, 0, 0);
          acc[ms][nf] = __builtin_amdgcn_mfma_f32_16x16x32_bf16(af[ms][1], bf[nf][1], acc[ms][nf], 0, 0, 0);
        }
      __syncthreads();
    }
  } else {
    for (int ks = 0; ks < 16; ++ks) {
      {
        const float4 f0 = *(const float4*)(asrcf + ks * 64);
        const float4 f1 = *(const float4*)(asrcf + ks * 64 + 4);
        const float4 f2 = *(const float4*)(asrcf + ks * 64 + 8);
        const float4 f3 = *(const float4*)(asrcf + ks * 64 + 12);
        u16x8 u0, u1;
        u0[0]=f2bf(f0.x); u0[1]=f2bf(f0.y); u0[2]=f2bf(f0.z); u0[3]=f2bf(f0.w);
        u0[4]=f2bf(f1.x); u0[5]=f2bf(f1.y); u0[6]=f2bf(f1.z); u0[7]=f2bf(f1.w);
        u1[0]=f2bf(f2.x); u1[1]=f2bf(f2.y); u1[2]=f2bf(f2.z); u1[3]=f2bf(f2.w);
        u1[4]=f2bf(f3.x); u1[5]=f2bf(f3.y); u1[6]=f2bf(f3.z); u1[7]=f2bf(f3.w);
        *(u16x8*)&As[sw64(ai, aseg * 16)]     = u0;
        *(u16x8*)&As[sw64(ai, aseg * 16 + 8)] = u1;
      }
      {
        const u32x4* bp = (const u32x4*)(bsrc + ks * 64);
#pragma unroll
        for (int j = 0; j < 4; ++j)
          *(u32x4*)&Bs[sw64(bn, bhf * 32 + j * 8)] = bp[j];
      }
      __syncthreads();
      bf16x8 af[2][2], bf[4][2];
#pragma unroll
      for (int ms = 0; ms < 2; ++ms)
#pragma unroll
        for (int kh = 0; kh < 2; ++kh)
          af[ms][kh] = *(const bf16x8*)&As[sw64(wr*32 + ms*16 + ln, kh*32 + lg*8)];
#pragma unroll
      for (int nf = 0; nf < 4; ++nf)
#pragma unroll
        for (int kh = 0; kh < 2; ++kh)
          bf[nf][kh] = *(const bf16x8*)&Bs[sw64(wc*64 + nf*16 + ln, kh*32 + lg*8)];
#pragma unroll
      for (int ms = 0; ms < 2; ++ms)
#pragma unroll
        for (int nf = 0; nf < 4; ++nf) {
          acc[ms][nf] = __builtin_amdgcn_mfma_f32_16x16x32_bf16(af[ms][0], bf[nf][0], acc[ms][nf], 0, 0, 0);
          acc[ms][nf] = __builtin_amdgcn_mfma_f32_16x16x32_bf16(af[ms][1], bf[nf][1], acc[ms][nf], 0, 0, 0);
        }
      __syncthreads();
    }
  }

  float b1c[4];
#pragma unroll
  for (int nf = 0; nf < 4; ++nf) b1c[nf] = b1[e * HID + wc*64 + nf*16 + ln];

#pragma unroll
  for (int ms = 0; ms < 2; ++ms)
#pragma unroll
    for (int r = 0; r < 4; ++r) {
      const int li = wr*32 + ms*16 + lg*4 + r;
      if (li < nr) {
        const int packed = rowl[li];
        const int row = packed >> 1, slot = packed & 1;
        const float2 tv = tval[row];
        const float v = slot ? tv.y : tv.x;
#pragma unroll
        for (int nf = 0; nf < 4; ++nf) {
          const float h = fmaxf(acc[ms][nf][r] + b1c[nf], 0.f) * v;
          Hg[((size_t)row * 2 + slot) * HID + wc*64 + nf*16 + ln] = f2bf(h);
        }
      }
    }
}

// ---------------------------------------------------------------------------
// K2: output GEMM, pair-grouped, with Bs reg-prefetch across the 4 ks steps.
// ---------------------------------------------------------------------------
__global__ __launch_bounds__(256) void k2_out(
    const unsigned short* __restrict__ Hg, const unsigned short* __restrict__ w2bt,
    const float* __restrict__ b2, const float2* __restrict__ tval,
    const int* __restrict__ plist, const int* __restrict__ hist,
    const int* __restrict__ base, const int* __restrict__ meta,
    float* __restrict__ out) {
  const int b = blockIdx.y;
  if (b >= meta[1]) return;
  const int item = meta[2 + MAXW1 + b];
  const int p = item >> 16, rt = item & 0xffff;
  const int ea = p / 7, rem = p % 7;
  const int eb = rem + (rem >= ea ? 1 : 0);
  const int start = rt * 64;
  const int nr = min(64, hist[p] - start);
  const int c0 = blockIdx.x * 128;

  __shared__ unsigned short Ah[64 * 256];   // swizzled, K=256 staged once
  __shared__ unsigned short Bs[128 * 64];   // swizzled, per-ks
  __shared__ int rowl[64];
  __shared__ float2 vals[64];

  const int t = threadIdx.x;
  if (t < 64) {
    const int r = plist[base[p] + start + (t < nr ? t : 0)];
    rowl[t] = r;
    vals[t] = tval[r];
  }
  __syncthreads();

  {
    const int i = t >> 2, q = t & 3;
    const u32x4* src = (const u32x4*)(Hg + (size_t)rowl[i] * 256 + q * 64);
#pragma unroll
    for (int j = 0; j < 8; ++j)
      *(u32x4*)&Ah[sw256(i, q * 64 + j * 8)] = src[j];
  }

  const int wid = t >> 6, l = t & 63;
  const int wr = wid >> 1, wc = wid & 1;
  const int lg = l >> 4,   ln = l & 15;

  f32x4 acc[2][4];
#pragma unroll
  for (int ms = 0; ms < 2; ++ms)
#pragma unroll
    for (int nf = 0; nf < 4; ++nf) acc[ms][nf] = (f32x4){0.f, 0.f, 0.f, 0.f};

  const int bn = t >> 1, bhf = t & 1;
  u32x4 breg[4];
  {
    const u32x4* bp = (const u32x4*)(
        w2bt + ((size_t)ea * NCLS + c0 + bn) * HID + bhf * 32);
#pragma unroll
    for (int j = 0; j < 4; ++j) breg[j] = bp[j];
  }
#pragma unroll
  for (int ks = 0; ks < 4; ++ks) {
#pragma unroll
    for (int j = 0; j < 4; ++j)
      *(u32x4*)&Bs[sw64(bn, bhf * 32 + j * 8)] = breg[j];
    __syncthreads();
    if (ks < 3) {   // prefetch next ks; hides under ds_read+MFMA
      const int exn = (ks + 1 < 2) ? ea : eb;
      const int hbn = ((ks + 1) & 1) * 64;
      const u32x4* bp = (const u32x4*)(
          w2bt + ((size_t)exn * NCLS + c0 + bn) * HID + hbn + bhf * 32);
#pragma unroll
      for (int j = 0; j < 4; ++j) breg[j] = bp[j];
    }
    bf16x8 af[2][2], bf[4][2];
#pragma unroll
    for (int ms = 0; ms < 2; ++ms)
#pragma unroll
      for (int kh = 0; kh < 2; ++kh)
        af[ms][kh] = *(const bf16x8*)&Ah[sw256(wr*32 + ms*16 + ln, ks*64 + kh*32 + lg*8)];
#pragma unroll
    for (int nf = 0; nf < 4; ++nf)
#pragma unroll
      for (int kh = 0; kh < 2; ++kh)
        bf[nf][kh] = *(const bf16x8*)&Bs[sw64(wc*64 + nf*16 + ln, kh*32 + lg*8)];
#pragma unroll
    for (int ms = 0; ms < 2; ++ms)
#pragma unroll
      for (int nf = 0; nf < 4; ++nf) {
        acc[ms][nf] = __builtin_amdgcn_mfma_f32_16x16x32_bf16(af[ms][0], bf[nf][0], acc[ms][nf], 0, 0, 0);
        acc[ms][nf] = __builtin_amdgcn_mfma_f32_16x16x32_bf16(af[ms][1], bf[nf][1], acc[ms][nf], 0, 0, 0);
      }
    __syncthreads();
  }

  float b2a[4], b2b[4];
#pragma unroll
  for (int nf = 0; nf < 4; ++nf) {
    const int c = c0 + wc*64 + nf*16 + ln;
    b2a[nf] = b2[ea * NCLS + c];
    b2b[nf] = b2[eb * NCLS + c];
  }
#pragma unroll
  for (int ms = 0; ms < 2; ++ms)
#pragma unroll
    for (int r = 0; r < 4; ++r) {
      const int li = wr*32 + ms*16 + lg*4 + r;
      if (li < nr) {
        const int row = rowl[li];
        const float2 v = vals[li];
#pragma unroll
        for (int nf = 0; nf < 4; ++nf) {
          const int c = c0 + wc*64 + nf*16 + ln;
          out[(size_t)row * NCLS + c] = acc[ms][nf][r] + v.x * b2a[nf] + v.y * b2b[nf];
        }
      }
    }
}

extern "C" void kernel_launch(void* const* d_in, const int* in_sizes, int n_in,
                              void* d_out, int out_size, void* d_ws, size_t ws_size,
                              hipStream_t stream) {
  const float* x   = (const float*)d_in[0];
  const float* gw  = (const float*)d_in[1];
  const float* gb  = (const float*)d_in[2];
  const float* w1  = (const float*)d_in[3];
  const float* b1  = (const float*)d_in[4];
  const float* w2  = (const float*)d_in[5];
  const float* b2  = (const float*)d_in[6];
  float* out = (float*)d_out;

  // ws layout (bytes). Nothing needs pre-zeroing:
  //   hist 0..256 | base 256..512 | csr 512..768 | meta 768..4104 (pad 4352)
  //   partials 4352..20736 | psum 20736..21248 | pairid 21248..37632
  //   tval 37632..168704 | elist 168704..299776 | plist 299776..365312
  //   w1bt 365312..2462464 | w2bt 2462464..4559616 | Hg 4559616..12948224
  //   xb  12948224..46502656 (optional)
  char* ws = (char*)d_ws;
  int*            hist     = (int*)(ws);
  int*            base     = (int*)(ws + 256);
  int*            csr      = (int*)(ws + 512);
  int*            meta     = (int*)(ws + 768);
  int*            partials = (int*)(ws + 4352);
  float2*         psum     = (float2*)(ws + 20736);
  unsigned char*  pairid   = (unsigned char*)(ws + 21248);
  float2*         tval     = (float2*)(ws + 37632);
  int*            elist    = (int*)(ws + 168704);
  int*            plist    = (int*)(ws + 299776);
  unsigned short* w1bt     = (unsigned short*)(ws + 365312);
  unsigned short* w2bt     = (unsigned short*)(ws + 2462464);
  unsigned short* Hg       = (unsigned short*)(ws + 4559616);
  const bool use_xb = (ws_size >= (size_t)46502656);
  unsigned short* xb = use_xb ? (unsigned short*)(ws + 12948224) : nullptr;

  prep_kernel<<<GATE_BLOCKS + W1T_BLOCKS + W2T_BLOCKS, 256, 0, stream>>>(
      x, gw, gb, w1, w2, xb, w1bt, w2bt, tval, pairid);
  hist_part_kernel<<<B_ROWS / 256, 256, 0, stream>>>(pairid, tval, partials, psum);
  scan_kernel<<<1, 64, 0, stream>>>(partials, psum, hist, base, csr, meta, out);
  scatter_kernel<<<B_ROWS / 256, 256, 0, stream>>>(pairid, csr, elist, plist);

  if (use_xb)
    k1_hidden<true><<<MAXW1, 256, 0, stream>>>(x, xb, w1bt, b1, tval, elist,
                                               hist, base, meta, Hg);
  else
    k1_hidden<false><<<MAXW1, 256, 0, stream>>>(x, xb, w1bt, b1, tval, elist,
                                                hist, base, meta, Hg);
  k2_out<<<dim3(NCLS / 128, MAXW2), 256, 0, stream>>>(Hg, w2bt, b2, tval, plist,
                                                      hist, base, meta, out);
}